// Round 10
// baseline (97.010 us; speedup 1.0000x reference)
//
#include <hip/hip_runtime.h>

#define VOUT_ELEMS 12582912   // 8*128*3*4096

typedef __attribute__((ext_vector_type(8))) short bf16x8;
typedef __attribute__((ext_vector_type(4))) float f32x4;

__device__ __forceinline__ unsigned short f2b(float f) {
  unsigned x = __float_as_uint(f);
  x = (x + 0x7FFFu + ((x >> 16) & 1u)) >> 16;
  return (unsigned short)x;
}
__device__ __forceinline__ float b2f(unsigned short u) {
  return __uint_as_float(((unsigned)u) << 16);
}
__device__ __forceinline__ unsigned pk2(float a, float b) {
  unsigned r;
  asm("v_cvt_pk_bf16_f32 %0, %1, %2" : "=v"(r) : "v"(a), "v"(b));
  return r;
}

// ws layout (bf16 elems): aW1@0, aW2@16384, aFC@32768, aVD@65536, aSV@81920,
// aVS@90112, aSS@98304.
// f32 at byte 204800 (wsf): [0:128) b2n, [128:256) bfcn, [256:384) bdirn,
// [384:512) rs1, [512:640) rs2, [640:768) rsF, [768:896) vdm (already /128).

__global__ void kprep0(const float* __restrict__ weight, const float* __restrict__ cross_w,
                       const float* __restrict__ crossfc_w, const float* __restrict__ vsdir_w,
                       const float* __restrict__ cross_b, const float* __restrict__ crossfc_b,
                       const float* __restrict__ vsdir_b, float* __restrict__ wsf)
{
  const int tid = threadIdx.x;              // 256
  const int l = tid & 63;
  const int wg = blockIdx.x*4 + (tid>>6);   // 0..63, 2 rows each
#pragma unroll
  for (int k = 0; k < 2; ++k) {
    int o = wg*2 + k;
    float a = weight[o*127+l]  + ((l<63) ? weight[o*127+64+l]  : 0.f);
    float b = cross_w[o*127+l] + ((l<63) ? cross_w[o*127+64+l] : 0.f);
    float f = crossfc_w[o*255+l] + crossfc_w[o*255+64+l] + crossfc_w[o*255+128+l]
            + ((l<63) ? crossfc_w[o*255+192+l] : 0.f);
    float v = vsdir_w[o*128+l] + vsdir_w[o*128+64+l];
#pragma unroll
    for (int m = 1; m < 64; m <<= 1) {
      a += __shfl_xor(a,m,64); b += __shfl_xor(b,m,64);
      f += __shfl_xor(f,m,64); v += __shfl_xor(v,m,64);
    }
    if (l == 0) {
      wsf[384+o] = a; wsf[512+o] = b; wsf[640+o] = f; wsf[768+o] = v*(1.f/128.f);
    }
  }
  if (blockIdx.x == 0 && tid < 192) {
    const float* bsrc = (tid < 64) ? cross_b : (tid < 128 ? crossfc_b : vsdir_b);
    float a = 0.f;
    for (int i = l; i < 128; i += 64) { float t = bsrc[i]; a += t*t; }
#pragma unroll
    for (int m = 1; m < 64; m <<= 1) a += __shfl_xor(a,m,64);
    float nb = fmaxf(sqrtf(a), 1e-12f);
    for (int i = l; i < 128; i += 64)
      wsf[(tid>>6)*128 + i] = bsrc[i] / nb * 1e-6f;
  }
}

__global__ void kprep1(const float* __restrict__ weight, const float* __restrict__ sv_w,
                       const float* __restrict__ cross_w, const float* __restrict__ crossfc_w,
                       const float* __restrict__ vsdir_w, const float* __restrict__ vs_w,
                       const float* __restrict__ ss_w,
                       unsigned short* __restrict__ wsb, const float* __restrict__ wsf)
{
  const int stride = 64*256;
  const int base = blockIdx.x*256 + threadIdx.x;
  const float* rs1 = wsf+384; const float* rs2 = wsf+512;
  const float* rsF = wsf+640; const float* vdm = wsf+768;
  for (int i = base; i < 16384; i += stride) {
    int j=i&7, lane=(i>>3)&63, ks=(i>>9)&3, mt=i>>11;
    int o=16*mt+(lane&15), cc=32*ks+8*(lane>>4)+j;
    wsb[i]       = f2b(cc<127 ? weight[o*127+cc]  : 1.f-rs1[o]);
    wsb[16384+i] = f2b(cc<127 ? cross_w[o*127+cc] : 1.f-rs2[o]);
    wsb[65536+i] = f2b(vsdir_w[o*128+cc] - vdm[o]);
  }
  for (int i = base; i < 32768; i += stride) {
    int j=i&7, lane=(i>>3)&63, ks=(i>>9)&7, mt=i>>12;
    int o=16*mt+(lane&15), cc=32*ks+8*(lane>>4)+j;
    wsb[32768+i] = f2b(cc<255 ? crossfc_w[o*255+cc] : 1.f-rsF[o]);
  }
  for (int i = base; i < 8192; i += stride) {
    int j=i&7, lane=(i>>3)&63, ks=(i>>9)&1, mt=i>>10;
    int o=16*mt+(lane&15), s=32*ks+8*(lane>>4)+j;
    wsb[81920+i] = f2b(sv_w[o*64+s]);
  }
  for (int i = base; i < 8192; i += stride) {
    int j=i&7, lane=(i>>3)&63, ks=(i>>9)&3, mt=i>>11;
    int o=16*mt+(lane&15), c=32*ks+8*(lane>>4)+j;
    wsb[90112+i] = f2b(vs_w[o*128+c]);
  }
  for (int i = base; i < 4096; i += stride) {
    int j=i&7, lane=(i>>3)&63, ks=(i>>9)&1, mt=i>>10;
    int o=16*mt+(lane&15), s=32*ks+8*(lane>>4)+j;
    wsb[98304+i] = f2b(ss_w[o*64+s]);
  }
}

// 256 threads, 4 waves; 16 sites/block; wave w owns M-tiles mt=w and mt=w+4.
// Barriers: B1 / B2 / B2b / B3.
// Register policy: amdgpu_waves_per_eu(5,5) pins exactly 5 waves/EU ->
// register budget 102/wave (no crush-to-64 spilling, no >128 occupancy cliff).
// adr (vsdir) GEMM after B2; ss-GEMM in phase C (as_s not live across B2->B3);
// moo analytic from round-1 sums; sfni deferred past VS GEMM.
__global__ __launch_bounds__(256) __attribute__((amdgpu_waves_per_eu(5,5)))
void kmain(
    const float* __restrict__ v_in, const float* __restrict__ s_in,
    const float* __restrict__ sv_b, const float* __restrict__ vs_b,
    const float* __restrict__ ss_b,
    const unsigned short* __restrict__ wsb, const float* __restrict__ wsf,
    float* __restrict__ out_v, float* __restrict__ out_s)
{
  __shared__ __align__(16) unsigned char smem[31232];
  unsigned short* bfr = (unsigned short*)smem;                  // 24576 B, slots 0..23
  float* gmx          = (float*)(smem + 12288);                 // 192 B  (alias slot 12)
  float (*gred)[16][4]  = (float(*)[16][4])(smem + 12480);      // 3072 B (alias slots 12..14)
  unsigned short* sfr = (unsigned short*)(smem + 24576);        // 2048 B
  unsigned short* vfr = (unsigned short*)(smem + 26624);        // 4096 B
  float (*gred2)[4]   = (float(*)[4])(smem + 30720);            // 256 B

  const int tid = threadIdx.x;
  const int w = tid >> 6, l = tid & 63, h = l >> 4, c15 = l & 15;
  const int n0 = blockIdx.x * 16;
  const size_t bb = blockIdx.y;
  const size_t vbase = bb*384*4096 + n0;
  const size_t sbase = bb*64*4096 + n0;

  // ---- phase A: quad-channel pair-packed scatter ----
  for (int i = tid; i < 384; i += 256) {        // (cq 0..31, d 0..2, q 0..3)
    int q = i & 3, d = (i >> 2) % 3, cq = i / 12;
    const float* src = &v_in[vbase + (size_t)(4*cq*3 + d)*4096 + 4*q];
    float4 x0 = *(const float4*)(src);
    float4 x1 = *(const float4*)(src + 3*4096);
    float4 x2 = *(const float4*)(src + 6*4096);
    float4 x3 = *(const float4*)(src + 9*4096);
    int slot = (cq >> 3)*3 + d;
    int hh = (cq >> 1) & 3;
    int jp = 2*(cq & 1);
    unsigned* bp = (unsigned*)bfr + (slot*64 + 16*hh + 4*q)*4 + jp;
    float a0[4]={x0.x,x0.y,x0.z,x0.w}, a1[4]={x1.x,x1.y,x1.z,x1.w};
    float a2[4]={x2.x,x2.y,x2.z,x2.w}, a3[4]={x3.x,x3.y,x3.z,x3.w};
#pragma unroll
    for (int e=0;e<4;++e)
      *(uint2*)(bp + e*4) = make_uint2(pk2(a0[e],a1[e]), pk2(a2[e],a3[e]));
  }
  if (tid < 64) {                               // (sq 0..15, q 0..3)
    int q = tid & 3, sq = tid >> 2;
    const float* src = &s_in[sbase + (size_t)(4*sq)*4096 + 4*q];
    float4 x0 = *(const float4*)(src);
    float4 x1 = *(const float4*)(src + 4096);
    float4 x2 = *(const float4*)(src + 2*4096);
    float4 x3 = *(const float4*)(src + 3*4096);
    int slot = sq >> 3;
    int hh = (sq >> 1) & 3;
    int jp = 2*(sq & 1);
    unsigned* bp = (unsigned*)sfr + (slot*64 + 16*hh + 4*q)*4 + jp;
    float a0[4]={x0.x,x0.y,x0.z,x0.w}, a1[4]={x1.x,x1.y,x1.z,x1.w};
    float a2[4]={x2.x,x2.y,x2.z,x2.w}, a3[4]={x3.x,x3.y,x3.z,x3.w};
#pragma unroll
    for (int e=0;e<4;++e)
      *(uint2*)(bp + e*4) = make_uint2(pk2(a0[e],a1[e]), pk2(a2[e],a3[e]));
  }
  __syncthreads();  // B1

  const bf16x8* bv  = (const bf16x8*)bfr;
  const bf16x8* sfv_p = (const bf16x8*)sfr;
  const bf16x8* vfv_p = (const bf16x8*)vfr;
  const bf16x8* wv  = (const bf16x8*)wsb;
  const int obA = 16*w + 4*h, obB = 16*(w+4) + 4*h;

  // ---- phase B: W1 (avo), W2 (adu), sv (asc), ones-GEMV ----
  f32x4 avo[2][3], adu[2][3], asc[2];
  {
    f32x4 b2A = *(const f32x4*)&wsf[obA],     b2B = *(const f32x4*)&wsf[obB];
#pragma unroll
    for (int d=0;d<3;++d) {
      avo[0][d]=(f32x4){0.f,0.f,0.f,0.f}; avo[1][d]=(f32x4){0.f,0.f,0.f,0.f};
      adu[0][d]=b2A; adu[1][d]=b2B;
    }
    asc[0] = *(const f32x4*)&sv_b[obA];
    asc[1] = *(const f32x4*)&sv_b[obB];
  }
#pragma unroll
  for (int ks=0;ks<4;++ks) {
    bf16x8 bx[3];
#pragma unroll
    for (int d=0;d<3;++d) bx[d] = bv[(ks*3+d)*64 + l];
#pragma unroll
    for (int mt=0;mt<2;++mt) {
      int fa = (w + 4*mt)*4 + ks;
      bf16x8 a1 = wv[fa*64 + l];
      bf16x8 a2 = wv[2048 + fa*64 + l];
#pragma unroll
      for (int d=0;d<3;++d) {
        avo[mt][d] = __builtin_amdgcn_mfma_f32_16x16x32_bf16(a1, bx[d], avo[mt][d], 0,0,0);
        adu[mt][d] = __builtin_amdgcn_mfma_f32_16x16x32_bf16(a2, bx[d], adu[mt][d], 0,0,0);
      }
    }
  }
#pragma unroll
  for (int ks=0;ks<2;++ks) {
    bf16x8 bs = sfv_p[ks*64 + l];
#pragma unroll
    for (int mt=0;mt<2;++mt) {
      bf16x8 a4 = wv[10240 + ((w+4*mt)*2+ks)*64 + l];
      asc[mt] = __builtin_amdgcn_mfma_f32_16x16x32_bf16(a4, bs, asc[mt], 0,0,0);
    }
  }
  if (w < 3) {  // x channel-mean via ones-row GEMV; wave w handles d=w
    bf16x8 aone;
#pragma unroll
    for (int j=0;j<8;++j) aone[j] = (short)0x3C00;  // bf16(1/128)
    f32x4 amx = (f32x4){0.f,0.f,0.f,0.f};
#pragma unroll
    for (int ks=0;ks<4;++ks)
      amx = __builtin_amdgcn_mfma_f32_16x16x32_bf16(aone, bv[(ks*3+w)*64+l], amx, 0,0,0);
    if (h==0) gmx[16*w + c15] = amx[0];
  }

  // ---- round-1 reductions: pv[3], pd[3], pd2, ps, pvs[3], Sa ----
  {
    float red[12];
#pragma unroll
    for (int d=0;d<3;++d) {
      red[d]   = avo[0][d][0]+avo[0][d][1]+avo[0][d][2]+avo[0][d][3]
               + avo[1][d][0]+avo[1][d][1]+avo[1][d][2]+avo[1][d][3];
      red[3+d] = adu[0][d][0]+adu[0][d][1]+adu[0][d][2]+adu[0][d][3]
               + adu[1][d][0]+adu[1][d][1]+adu[1][d][2]+adu[1][d][3];
      red[8+d] = avo[0][d][0]*asc[0][0]+avo[0][d][1]*asc[0][1]
               + avo[0][d][2]*asc[0][2]+avo[0][d][3]*asc[0][3]
               + avo[1][d][0]*asc[1][0]+avo[1][d][1]*asc[1][1]
               + avo[1][d][2]*asc[1][2]+avo[1][d][3]*asc[1][3];
    }
    float q2 = 0.f;
#pragma unroll
    for (int mt=0;mt<2;++mt)
#pragma unroll
      for (int d=0;d<3;++d)
#pragma unroll
        for (int r=0;r<4;++r) q2 += adu[mt][d][r]*adu[mt][d][r];
    red[6] = q2;
    red[7] = asc[0][0]*asc[0][0]+asc[0][1]*asc[0][1]+asc[0][2]*asc[0][2]+asc[0][3]*asc[0][3]
           + asc[1][0]*asc[1][0]+asc[1][1]*asc[1][1]+asc[1][2]*asc[1][2]+asc[1][3]*asc[1][3];
    red[11]= asc[0][0]+asc[0][1]+asc[0][2]+asc[0][3]
           + asc[1][0]+asc[1][1]+asc[1][2]+asc[1][3];
#pragma unroll
    for (int m=16;m<64;m<<=1)
#pragma unroll
      for (int i=0;i<12;++i) red[i] += __shfl_xor(red[i], m, 64);
    if (h==0)
#pragma unroll
      for (int i=0;i<12;++i) gred[i][c15][w] = red[i];
  }
  __syncthreads(); // B2

  float mvo[3], mdu[3], mxv[3], moo[3], d2s, sinv, Sa;
  { f32x4 t = *(const f32x4*)gred[7][c15];
    sinv = 1.f / fmaxf(sqrtf(t[0]+t[1]+t[2]+t[3]), 1e-12f); }
  { f32x4 t = *(const f32x4*)gred[11][c15]; Sa = t[0]+t[1]+t[2]+t[3]; }
  { f32x4 t = *(const f32x4*)gred[6][c15];  d2s = t[0]+t[1]+t[2]+t[3]; }
#pragma unroll
  for (int d=0;d<3;++d) {
    f32x4 t = *(const f32x4*)gred[d][c15];
    f32x4 u = *(const f32x4*)gred[3+d][c15];
    f32x4 v = *(const f32x4*)gred[8+d][c15];
    mvo[d] = (t[0]+t[1]+t[2]+t[3]) * (1.f/128.f);
    mdu[d] = (u[0]+u[1]+u[2]+u[3]) * (1.f/128.f);
    float Svs = v[0]+v[1]+v[2]+v[3];
    moo[d] = mvo[d] + sinv*(Svs - mvo[d]*Sa)*(1.f/128.f);
    mxv[d] = gmx[16*d + c15];
  }

  // apply invariant scale
#pragma unroll
  for (int mt=0;mt<2;++mt)
#pragma unroll
    for (int r=0;r<4;++r) {
      float sk = asc[mt][r] * sinv;
#pragma unroll
      for (int d=0;d<3;++d)
        avo[mt][d][r] = (avo[mt][d][r]-mvo[d])*sk + mvo[d];
    }

  // ---- adr (vsdir) GEMM here: x-slots of bfr still valid until post-B2b ----
  f32x4 adr[2][3];
  {
    f32x4 bdA = *(const f32x4*)&wsf[256+obA], bdB = *(const f32x4*)&wsf[256+obB];
#pragma unroll
    for (int d=0;d<3;++d) { adr[0][d]=bdA; adr[1][d]=bdB; }
  }
#pragma unroll
  for (int ks=0;ks<4;++ks) {
    bf16x8 bx[3];
#pragma unroll
    for (int d=0;d<3;++d) bx[d] = bv[(ks*3+d)*64 + l];
#pragma unroll
    for (int mt=0;mt<2;++mt) {
      bf16x8 a3 = wv[8192 + ((w+4*mt)*4+ks)*64 + l];
#pragma unroll
      for (int d=0;d<3;++d)
        adr[mt][d] = __builtin_amdgcn_mfma_f32_16x16x32_bf16(a3, bx[d], adr[mt][d], 0,0,0);
    }
  }

  // v_sR readback (ephemeral) + dir-normalized invariant dot (raw; sfni deferred)
  float sfvv[2][4]; float pfn = 0.f;
#pragma unroll
  for (int mt=0;mt<2;++mt) {
    int c0 = 16*(w+4*mt) + 4*h;
    int ksq = c0 >> 5, hh = (c0>>3)&3, ju = 2*(h&1);
    float xr[3][4];
#pragma unroll
    for (int d=0;d<3;++d) {
      uint2 u = *(const uint2*)((const unsigned*)bfr + ((ksq*3+d)*64 + 16*hh + c15)*4 + ju);
      xr[d][0]=b2f((unsigned short)u.x);  xr[d][1]=b2f((unsigned short)(u.x>>16));
      xr[d][2]=b2f((unsigned short)u.y);  xr[d][3]=b2f((unsigned short)(u.y>>16));
    }
#pragma unroll
    for (int r=0;r<4;++r) {
      float dx=adr[mt][0][r], dy=adr[mt][1][r], dz=adr[mt][2][r];
      float rn = sqrtf(dx*dx+dy*dy+dz*dz);
      float inv = 1.f/fmaxf(rn,1e-12f);
      float vx = xr[0][r]-mxv[0], vy = xr[1][r]-mxv[1], vz = xr[2][r]-mxv[2];
      float dot = (vx*dx+vy*dy+vz*dz)*inv;
      sfvv[mt][r] = dot; pfn += dot*dot;
    }
  }
  pfn += __shfl_xor(pfn,16,64); pfn += __shfl_xor(pfn,32,64);
  if (h==0) gred2[c15][w] = pfn;
  __syncthreads(); // B2b (fences xr/bv reads before xd/xo writes; gred2 complete)

  // cross-product + fragment writes (own channels only)
  float m2 = mdu[0]*mdu[0]+mdu[1]*mdu[1]+mdu[2]*mdu[2];
  float F  = sqrtf(fmaxf(d2s - 128.f*m2, 0.f));
  float Fi = 1.f/fmaxf(F, 1e-12f);
#pragma unroll
  for (int mt=0;mt<2;++mt) {
    int c0 = 16*(w+4*mt) + 4*h;
    int ksq = c0 >> 5, hh = (c0>>3)&3, ju = 2*(h&1);
    *(uint2*)((unsigned*)vfr + (ksq*64 + 16*hh + c15)*4 + ju) =
      make_uint2(pk2(sfvv[mt][0], sfvv[mt][1]), pk2(sfvv[mt][2], sfvv[mt][3]));
    float cv[3][4];
#pragma unroll
    for (int r=0;r<4;++r) {
      float ax=adu[mt][0][r]-mdu[0], ay=adu[mt][1][r]-mdu[1], az=adu[mt][2][r]-mdu[2];
      float rn = sqrtf(ax*ax+ay*ay+az*az);
      float s1 = (rn*Fi)/fmaxf(rn,1e-12f);
      ax*=s1; ay*=s1; az*=s1;
      float bx=avo[mt][0][r]-moo[0], by=avo[mt][1][r]-moo[1], bz=avo[mt][2][r]-moo[2];
      cv[0][r]=ay*bz-az*by+avo[mt][0][r];
      cv[1][r]=az*bx-ax*bz+avo[mt][1][r];
      cv[2][r]=ax*by-ay*bx+avo[mt][2][r];
    }
#pragma unroll
    for (int d=0;d<3;++d) {
      *(uint2*)((unsigned*)bfr + ((ksq*3+d)*64 + 16*hh + c15)*4 + ju) =
        make_uint2(pk2(cv[d][0],cv[d][1]), pk2(cv[d][2],cv[d][3]));
      *(uint2*)((unsigned*)bfr + (((4+ksq)*3+d)*64 + 16*hh + c15)*4 + ju) =
        make_uint2(pk2(avo[mt][d][0],avo[mt][d][1]), pk2(avo[mt][d][2],avo[mt][d][3]));
    }
  }
  __syncthreads(); // B3

  // ---- phase C: crossfc (K=256) + VS GEMM + ss GEMM ----
  f32x4 afc[2][3];
  {
    f32x4 bfA = *(const f32x4*)&wsf[128+obA], bfB = *(const f32x4*)&wsf[128+obB];
#pragma unroll
    for (int d=0;d<3;++d) { afc[0][d]=bfA; afc[1][d]=bfB; }
  }
#pragma unroll
  for (int ks=0;ks<8;++ks) {
    bf16x8 bx[3];
#pragma unroll
    for (int d=0;d<3;++d) bx[d] = bv[(ks*3+d)*64 + l];
#pragma unroll
    for (int mt=0;mt<2;++mt) {
      bf16x8 a5 = wv[4096 + ((w+4*mt)*8+ks)*64 + l];
#pragma unroll
      for (int d=0;d<3;++d)
        afc[mt][d] = __builtin_amdgcn_mfma_f32_16x16x32_bf16(a5, bx[d], afc[mt][d], 0,0,0);
    }
  }
  f32x4 as_v = (f32x4){0.f,0.f,0.f,0.f};
#pragma unroll
  for (int ks=0;ks<4;++ks) {
    bf16x8 a6 = wv[11264 + (w*4+ks)*64 + l];
    as_v = __builtin_amdgcn_mfma_f32_16x16x32_bf16(a6, vfv_p[ks*64+l], as_v, 0,0,0);
  }
  f32x4 as_s;
  {
    f32x4 bv1 = *(const f32x4*)&vs_b[obA];
    f32x4 bv2 = *(const f32x4*)&ss_b[obA];
    as_s = (f32x4){bv1[0]+bv2[0], bv1[1]+bv2[1], bv1[2]+bv2[2], bv1[3]+bv2[3]};
#pragma unroll
    for (int ks=0;ks<2;++ks) {
      bf16x8 a7 = wv[12288 + (w*2+ks)*64 + l];
      as_s = __builtin_amdgcn_mfma_f32_16x16x32_bf16(a7, sfv_p[ks*64+l], as_s, 0,0,0);
    }
  }
  float sfni;
  { f32x4 t = *(const f32x4*)gred2[c15];
    sfni = 1.f/fmaxf(sqrtf(t[0]+t[1]+t[2]+t[3]), 1e-12f); }

  // ---- epilogue: direct global stores ----
#pragma unroll
  for (int mt=0;mt<2;++mt) {
    int c0 = 16*(w+4*mt) + 4*h;
#pragma unroll
    for (int d=0;d<3;++d)
#pragma unroll
      for (int r=0;r<4;++r)
        out_v[vbase + (size_t)((c0+r)*3 + d)*4096 + c15] = afc[mt][d][r];
  }
#pragma unroll
  for (int r=0;r<4;++r)
    out_s[sbase + (size_t)(obA+r)*4096 + c15] = as_s[r] + as_v[r]*sfni;
}

extern "C" void kernel_launch(void* const* d_in, const int* in_sizes, int n_in,
                              void* d_out, int out_size, void* d_ws, size_t ws_size,
                              hipStream_t stream) {
  (void)in_sizes; (void)n_in; (void)out_size; (void)ws_size;
  const float* v_in      = (const float*)d_in[0];
  const float* s_in      = (const float*)d_in[1];
  const float* weight    = (const float*)d_in[2];
  const float* sv_w      = (const float*)d_in[3];
  const float* sv_b      = (const float*)d_in[4];
  const float* cross_w   = (const float*)d_in[5];
  const float* cross_b   = (const float*)d_in[6];
  const float* crossfc_w = (const float*)d_in[7];
  const float* crossfc_b = (const float*)d_in[8];
  const float* vsdir_w   = (const float*)d_in[9];
  const float* vsdir_b   = (const float*)d_in[10];
  const float* vs_w      = (const float*)d_in[11];
  const float* vs_b      = (const float*)d_in[12];
  const float* ss_w      = (const float*)d_in[13];
  const float* ss_b      = (const float*)d_in[14];

  unsigned short* wsb = (unsigned short*)d_ws;
  float* wsf = (float*)((char*)d_ws + 204800);

  kprep0<<<16, 256, 0, stream>>>(weight, cross_w, crossfc_w, vsdir_w,
                                 cross_b, crossfc_b, vsdir_b, wsf);
  kprep1<<<64, 256, 0, stream>>>(weight, sv_w, cross_w, crossfc_w, vsdir_w,
                                 vs_w, ss_w, wsb, wsf);
  dim3 grid(4096/16, 8);
  kmain<<<grid, 256, 0, stream>>>(v_in, s_in, sv_b, vs_b, ss_b, wsb, wsf,
                                  (float*)d_out, (float*)d_out + VOUT_ELEMS);
}

// Round 11
// 64.211 us; speedup vs baseline: 1.5108x; 1.5108x over previous
//
#include <hip/hip_runtime.h>

#define VOUT_ELEMS 12582912   // 8*128*3*4096

typedef __attribute__((ext_vector_type(8))) short bf16x8;
typedef __attribute__((ext_vector_type(4))) float f32x4;

__device__ __forceinline__ unsigned short f2b(float f) {
  unsigned x = __float_as_uint(f);
  x = (x + 0x7FFFu + ((x >> 16) & 1u)) >> 16;
  return (unsigned short)x;
}
__device__ __forceinline__ float b2f(unsigned short u) {
  return __uint_as_float(((unsigned)u) << 16);
}
__device__ __forceinline__ unsigned pk2(float a, float b) {
  unsigned r;
  asm("v_cvt_pk_bf16_f32 %0, %1, %2" : "=v"(r) : "v"(a), "v"(b));
  return r;
}

// ws layout (bf16 elems): aW1@0, aW2@16384, aFC@32768, aVD@65536, aSV@81920,
// aVS@90112, aSS@98304.
// f32 at byte 204800 (wsf): [0:128) b2n, [128:256) bfcn, [256:384) bdirn,
// [384:512) rs1, [512:640) rs2, [640:768) rsF, [768:896) vdm (already /128).

__global__ void kprep0(const float* __restrict__ weight, const float* __restrict__ cross_w,
                       const float* __restrict__ crossfc_w, const float* __restrict__ vsdir_w,
                       const float* __restrict__ cross_b, const float* __restrict__ crossfc_b,
                       const float* __restrict__ vsdir_b, float* __restrict__ wsf)
{
  const int tid = threadIdx.x;              // 256
  const int l = tid & 63;
  const int wg = blockIdx.x*4 + (tid>>6);   // 0..63, 2 rows each
#pragma unroll
  for (int k = 0; k < 2; ++k) {
    int o = wg*2 + k;
    float a = weight[o*127+l]  + ((l<63) ? weight[o*127+64+l]  : 0.f);
    float b = cross_w[o*127+l] + ((l<63) ? cross_w[o*127+64+l] : 0.f);
    float f = crossfc_w[o*255+l] + crossfc_w[o*255+64+l] + crossfc_w[o*255+128+l]
            + ((l<63) ? crossfc_w[o*255+192+l] : 0.f);
    float v = vsdir_w[o*128+l] + vsdir_w[o*128+64+l];
#pragma unroll
    for (int m = 1; m < 64; m <<= 1) {
      a += __shfl_xor(a,m,64); b += __shfl_xor(b,m,64);
      f += __shfl_xor(f,m,64); v += __shfl_xor(v,m,64);
    }
    if (l == 0) {
      wsf[384+o] = a; wsf[512+o] = b; wsf[640+o] = f; wsf[768+o] = v*(1.f/128.f);
    }
  }
  if (blockIdx.x == 0 && tid < 192) {
    const float* bsrc = (tid < 64) ? cross_b : (tid < 128 ? crossfc_b : vsdir_b);
    float a = 0.f;
    for (int i = l; i < 128; i += 64) { float t = bsrc[i]; a += t*t; }
#pragma unroll
    for (int m = 1; m < 64; m <<= 1) a += __shfl_xor(a,m,64);
    float nb = fmaxf(sqrtf(a), 1e-12f);
    for (int i = l; i < 128; i += 64)
      wsf[(tid>>6)*128 + i] = bsrc[i] / nb * 1e-6f;
  }
}

__global__ void kprep1(const float* __restrict__ weight, const float* __restrict__ sv_w,
                       const float* __restrict__ cross_w, const float* __restrict__ crossfc_w,
                       const float* __restrict__ vsdir_w, const float* __restrict__ vs_w,
                       const float* __restrict__ ss_w,
                       unsigned short* __restrict__ wsb, const float* __restrict__ wsf)
{
  const int stride = 64*256;
  const int base = blockIdx.x*256 + threadIdx.x;
  const float* rs1 = wsf+384; const float* rs2 = wsf+512;
  const float* rsF = wsf+640; const float* vdm = wsf+768;
  for (int i = base; i < 16384; i += stride) {
    int j=i&7, lane=(i>>3)&63, ks=(i>>9)&3, mt=i>>11;
    int o=16*mt+(lane&15), cc=32*ks+8*(lane>>4)+j;
    wsb[i]       = f2b(cc<127 ? weight[o*127+cc]  : 1.f-rs1[o]);
    wsb[16384+i] = f2b(cc<127 ? cross_w[o*127+cc] : 1.f-rs2[o]);
    wsb[65536+i] = f2b(vsdir_w[o*128+cc] - vdm[o]);
  }
  for (int i = base; i < 32768; i += stride) {
    int j=i&7, lane=(i>>3)&63, ks=(i>>9)&7, mt=i>>12;
    int o=16*mt+(lane&15), cc=32*ks+8*(lane>>4)+j;
    wsb[32768+i] = f2b(cc<255 ? crossfc_w[o*255+cc] : 1.f-rsF[o]);
  }
  for (int i = base; i < 8192; i += stride) {
    int j=i&7, lane=(i>>3)&63, ks=(i>>9)&1, mt=i>>10;
    int o=16*mt+(lane&15), s=32*ks+8*(lane>>4)+j;
    wsb[81920+i] = f2b(sv_w[o*64+s]);
  }
  for (int i = base; i < 8192; i += stride) {
    int j=i&7, lane=(i>>3)&63, ks=(i>>9)&3, mt=i>>11;
    int o=16*mt+(lane&15), c=32*ks+8*(lane>>4)+j;
    wsb[90112+i] = f2b(vs_w[o*128+c]);
  }
  for (int i = base; i < 4096; i += stride) {
    int j=i&7, lane=(i>>3)&63, ks=(i>>9)&1, mt=i>>10;
    int o=16*mt+(lane&15), s=32*ks+8*(lane>>4)+j;
    wsb[98304+i] = f2b(ss_w[o*64+s]);
  }
}

// 512 threads, 8 waves; 16 sites/block; wave w owns ONE M-tile mt=w.
// R6 barrier skeleton: B1 / B2 / B2b / B3; two reduction rounds.
// Live-across-B2 accumulators: avo+adu+adr (12 ea) + asc (4) = 40 floats/thread.
// amdgpu_waves_per_eu(4): 128-reg budget, comfortable for the halved live set.
// gmx+gred alias bfr's xo-slot region (written/read before B2b; xo written after).
__global__ __launch_bounds__(512) __attribute__((amdgpu_waves_per_eu(4)))
void kmain(
    const float* __restrict__ v_in, const float* __restrict__ s_in,
    const float* __restrict__ sv_b, const float* __restrict__ vs_b,
    const float* __restrict__ ss_b,
    const unsigned short* __restrict__ wsb, const float* __restrict__ wsf,
    float* __restrict__ out_v, float* __restrict__ out_s)
{
  __shared__ __align__(16) unsigned char smem[32768];
  unsigned short* bfr = (unsigned short*)smem;                  // 24576 B, slots 0..23
  float* gmx          = (float*)(smem + 12288);                 // 192 B  (alias slot 12)
  float (*gred)[16][8]  = (float(*)[16][8])(smem + 12480);      // 4096 B (alias slots 12..16)
  unsigned short* sfr = (unsigned short*)(smem + 24576);        // 2048 B
  unsigned short* vfr = (unsigned short*)(smem + 26624);        // 4096 B
  float (*gred2)[16][8] = (float(*)[16][8])(smem + 30720);      // 2048 B

  const int tid = threadIdx.x;
  const int w = tid >> 6, l = tid & 63, h = l >> 4, c15 = l & 15;
  const int n0 = blockIdx.x * 16;
  const size_t bb = blockIdx.y;
  const size_t vbase = bb*384*4096 + n0;
  const size_t sbase = bb*64*4096 + n0;

  // ---- phase A: quad-channel pair-packed scatter ----
  if (tid < 384) {                              // (cq 0..31, d 0..2, q 0..3)
    int i = tid;
    int q = i & 3, d = (i >> 2) % 3, cq = i / 12;
    const float* src = &v_in[vbase + (size_t)(4*cq*3 + d)*4096 + 4*q];
    float4 x0 = *(const float4*)(src);
    float4 x1 = *(const float4*)(src + 3*4096);
    float4 x2 = *(const float4*)(src + 6*4096);
    float4 x3 = *(const float4*)(src + 9*4096);
    int slot = (cq >> 3)*3 + d;
    int hh = (cq >> 1) & 3;
    int jp = 2*(cq & 1);
    unsigned* bp = (unsigned*)bfr + (slot*64 + 16*hh + 4*q)*4 + jp;
    float a0[4]={x0.x,x0.y,x0.z,x0.w}, a1[4]={x1.x,x1.y,x1.z,x1.w};
    float a2[4]={x2.x,x2.y,x2.z,x2.w}, a3[4]={x3.x,x3.y,x3.z,x3.w};
#pragma unroll
    for (int e=0;e<4;++e)
      *(uint2*)(bp + e*4) = make_uint2(pk2(a0[e],a1[e]), pk2(a2[e],a3[e]));
  } else if (tid < 448) {                       // (sq 0..15, q 0..3)
    int st = tid - 384;
    int q = st & 3, sq = st >> 2;
    const float* src = &s_in[sbase + (size_t)(4*sq)*4096 + 4*q];
    float4 x0 = *(const float4*)(src);
    float4 x1 = *(const float4*)(src + 4096);
    float4 x2 = *(const float4*)(src + 2*4096);
    float4 x3 = *(const float4*)(src + 3*4096);
    int slot = sq >> 3;
    int hh = (sq >> 1) & 3;
    int jp = 2*(sq & 1);
    unsigned* bp = (unsigned*)sfr + (slot*64 + 16*hh + 4*q)*4 + jp;
    float a0[4]={x0.x,x0.y,x0.z,x0.w}, a1[4]={x1.x,x1.y,x1.z,x1.w};
    float a2[4]={x2.x,x2.y,x2.z,x2.w}, a3[4]={x3.x,x3.y,x3.z,x3.w};
#pragma unroll
    for (int e=0;e<4;++e)
      *(uint2*)(bp + e*4) = make_uint2(pk2(a0[e],a1[e]), pk2(a2[e],a3[e]));
  }
  __syncthreads();  // B1

  const bf16x8* bv  = (const bf16x8*)bfr;
  const bf16x8* sfv_p = (const bf16x8*)sfr;
  const bf16x8* vfv_p = (const bf16x8*)vfr;
  const bf16x8* wv  = (const bf16x8*)wsb;
  const int obA = 16*w + 4*h;          // this wave's output-row base

  // ---- phase B: W1 (avo), W2 (adu), Vdir (adr), sv (asc), ones-GEMV ----
  f32x4 avo[3], adu[3], adr[3], asc;
  {
    f32x4 b2A = *(const f32x4*)&wsf[obA];
    f32x4 bdA = *(const f32x4*)&wsf[256+obA];
#pragma unroll
    for (int d=0;d<3;++d) {
      avo[d]=(f32x4){0.f,0.f,0.f,0.f};
      adu[d]=b2A;
      adr[d]=bdA;
    }
    asc = *(const f32x4*)&sv_b[obA];
  }
#pragma unroll
  for (int ks=0;ks<4;++ks) {
    bf16x8 bx[3];
#pragma unroll
    for (int d=0;d<3;++d) bx[d] = bv[(ks*3+d)*64 + l];
    int fa = w*4 + ks;
    bf16x8 a1 = wv[fa*64 + l];
    bf16x8 a2 = wv[2048 + fa*64 + l];
    bf16x8 a3 = wv[8192 + fa*64 + l];
#pragma unroll
    for (int d=0;d<3;++d) {
      avo[d] = __builtin_amdgcn_mfma_f32_16x16x32_bf16(a1, bx[d], avo[d], 0,0,0);
      adu[d] = __builtin_amdgcn_mfma_f32_16x16x32_bf16(a2, bx[d], adu[d], 0,0,0);
      adr[d] = __builtin_amdgcn_mfma_f32_16x16x32_bf16(a3, bx[d], adr[d], 0,0,0);
    }
  }
#pragma unroll
  for (int ks=0;ks<2;++ks) {
    bf16x8 a4 = wv[10240 + (w*2+ks)*64 + l];
    asc = __builtin_amdgcn_mfma_f32_16x16x32_bf16(a4, sfv_p[ks*64+l], asc, 0,0,0);
  }
  if (w < 3) {  // x channel-mean via ones-row GEMV; wave w handles d=w
    bf16x8 aone;
#pragma unroll
    for (int j=0;j<8;++j) aone[j] = (short)0x3C00;  // bf16(1/128)
    f32x4 amx = (f32x4){0.f,0.f,0.f,0.f};
#pragma unroll
    for (int ks=0;ks<4;++ks)
      amx = __builtin_amdgcn_mfma_f32_16x16x32_bf16(aone, bv[(ks*3+w)*64+l], amx, 0,0,0);
    if (h==0) gmx[16*w + c15] = amx[0];
  }

  // ---- round-1 reductions: pv[3], pd[3], pd2, ps ----
  {
    float red[8];
#pragma unroll
    for (int d=0;d<3;++d) {
      red[d]   = avo[d][0]+avo[d][1]+avo[d][2]+avo[d][3];
      red[3+d] = adu[d][0]+adu[d][1]+adu[d][2]+adu[d][3];
    }
    float q2 = 0.f;
#pragma unroll
    for (int d=0;d<3;++d)
#pragma unroll
      for (int r=0;r<4;++r) q2 += adu[d][r]*adu[d][r];
    red[6] = q2;
    red[7] = asc[0]*asc[0]+asc[1]*asc[1]+asc[2]*asc[2]+asc[3]*asc[3];
#pragma unroll
    for (int m=16;m<64;m<<=1)
#pragma unroll
      for (int i=0;i<8;++i) red[i] += __shfl_xor(red[i], m, 64);
    if (h==0)
#pragma unroll
      for (int i=0;i<8;++i) gred[i][c15][w] = red[i];
  }
  __syncthreads(); // B2

  float mvo[3], mdu[3], mxv[3], d2s, sinv;
#pragma unroll
  for (int d=0;d<3;++d) {
    const f32x4* p  = (const f32x4*)gred[d][c15];
    const f32x4* p2 = (const f32x4*)gred[3+d][c15];
    f32x4 t0=p[0], t1=p[1], u0=p2[0], u1=p2[1];
    mvo[d] = (t0[0]+t0[1]+t0[2]+t0[3]+t1[0]+t1[1]+t1[2]+t1[3]) * (1.f/128.f);
    mdu[d] = (u0[0]+u0[1]+u0[2]+u0[3]+u1[0]+u1[1]+u1[2]+u1[3]) * (1.f/128.f);
    mxv[d] = gmx[16*d + c15];
  }
  { const f32x4* p = (const f32x4*)gred[6][c15];
    f32x4 t0=p[0], t1=p[1];
    d2s = t0[0]+t0[1]+t0[2]+t0[3]+t1[0]+t1[1]+t1[2]+t1[3]; }
  { const f32x4* p = (const f32x4*)gred[7][c15];
    f32x4 t0=p[0], t1=p[1];
    sinv = 1.f / fmaxf(sqrtf(t0[0]+t0[1]+t0[2]+t0[3]+t1[0]+t1[1]+t1[2]+t1[3]), 1e-12f); }

  // apply invariant scale; po partials
  float po[3] = {0.f,0.f,0.f};
#pragma unroll
  for (int r=0;r<4;++r) {
    float sk = asc[r] * sinv;
#pragma unroll
    for (int d=0;d<3;++d) {
      float t = (avo[d][r]-mvo[d])*sk + mvo[d];
      avo[d][r] = t;
      po[d] += t;
    }
  }

  // v_sR readback (ephemeral) + dir-normalized invariant dot
  const int ksq = w >> 1;
  const int hh2 = 2*(w&1) + (h>>1);
  const int ju = 2*(h&1);
  float sfvv[4]; float pfn = 0.f;
  {
    float xr[3][4];
#pragma unroll
    for (int d=0;d<3;++d) {
      uint2 u = *(const uint2*)((const unsigned*)bfr + ((ksq*3+d)*64 + 16*hh2 + c15)*4 + ju);
      xr[d][0]=b2f((unsigned short)u.x);  xr[d][1]=b2f((unsigned short)(u.x>>16));
      xr[d][2]=b2f((unsigned short)u.y);  xr[d][3]=b2f((unsigned short)(u.y>>16));
    }
#pragma unroll
    for (int r=0;r<4;++r) {
      float dx=adr[0][r], dy=adr[1][r], dz=adr[2][r];
      float rn = sqrtf(dx*dx+dy*dy+dz*dz);
      float inv = 1.f/fmaxf(rn,1e-12f);
      float vx = xr[0][r]-mxv[0], vy = xr[1][r]-mxv[1], vz = xr[2][r]-mxv[2];
      float dot = (vx*dx+vy*dy+vz*dz)*inv;
      sfvv[r] = dot; pfn += dot*dot;
    }
  }

  // ---- round-2 reductions: po[3], pfn ----
  {
    float red2[4] = {po[0], po[1], po[2], pfn};
#pragma unroll
    for (int m=16;m<64;m<<=1)
#pragma unroll
      for (int i=0;i<4;++i) red2[i] += __shfl_xor(red2[i], m, 64);
    if (h==0)
#pragma unroll
      for (int i=0;i<4;++i) gred2[i][c15][w] = red2[i];
  }
  __syncthreads(); // B2b (fences xr/gmx/gred reads before xd/xo writes)

  float moo[3], sfni;
#pragma unroll
  for (int d=0;d<3;++d) {
    const f32x4* p = (const f32x4*)gred2[d][c15];
    f32x4 t0=p[0], t1=p[1];
    moo[d] = (t0[0]+t0[1]+t0[2]+t0[3]+t1[0]+t1[1]+t1[2]+t1[3]) * (1.f/128.f);
  }
  { const f32x4* p = (const f32x4*)gred2[3][c15];
    f32x4 t0=p[0], t1=p[1];
    sfni = 1.f/fmaxf(sqrtf(t0[0]+t0[1]+t0[2]+t0[3]+t1[0]+t1[1]+t1[2]+t1[3]), 1e-12f); }

  // cross-product + fragment writes (own channels only)
  float m2 = mdu[0]*mdu[0]+mdu[1]*mdu[1]+mdu[2]*mdu[2];
  float F  = sqrtf(fmaxf(d2s - 128.f*m2, 0.f));
  float Fi = 1.f/fmaxf(F, 1e-12f);
  {
    *(uint2*)((unsigned*)vfr + (ksq*64 + 16*hh2 + c15)*4 + ju) =
      make_uint2(pk2(sfvv[0]*sfni, sfvv[1]*sfni),
                 pk2(sfvv[2]*sfni, sfvv[3]*sfni));
    float cv[3][4];
#pragma unroll
    for (int r=0;r<4;++r) {
      float ax=adu[0][r]-mdu[0], ay=adu[1][r]-mdu[1], az=adu[2][r]-mdu[2];
      float rn = sqrtf(ax*ax+ay*ay+az*az);
      float s1 = (rn*Fi)/fmaxf(rn,1e-12f);
      ax*=s1; ay*=s1; az*=s1;
      float bx=avo[0][r]-moo[0], by=avo[1][r]-moo[1], bz=avo[2][r]-moo[2];
      cv[0][r]=ay*bz-az*by+avo[0][r];
      cv[1][r]=az*bx-ax*bz+avo[1][r];
      cv[2][r]=ax*by-ay*bx+avo[2][r];
    }
#pragma unroll
    for (int d=0;d<3;++d) {
      *(uint2*)((unsigned*)bfr + ((ksq*3+d)*64 + 16*hh2 + c15)*4 + ju) =
        make_uint2(pk2(cv[d][0],cv[d][1]), pk2(cv[d][2],cv[d][3]));
      *(uint2*)((unsigned*)bfr + (((4+ksq)*3+d)*64 + 16*hh2 + c15)*4 + ju) =
        make_uint2(pk2(avo[d][0],avo[d][1]), pk2(avo[d][2],avo[d][3]));
    }
  }
  __syncthreads(); // B3

  // ---- phase C: crossfc (K=256) + VS/SS GEMMs (waves 0..3) ----
  f32x4 afc[3];
  {
    f32x4 bfA = *(const f32x4*)&wsf[128+obA];
#pragma unroll
    for (int d=0;d<3;++d) afc[d]=bfA;
  }
#pragma unroll
  for (int ks=0;ks<8;++ks) {
    bf16x8 bx[3];
#pragma unroll
    for (int d=0;d<3;++d) bx[d] = bv[(ks*3+d)*64 + l];
    bf16x8 a5 = wv[4096 + (w*8+ks)*64 + l];
#pragma unroll
    for (int d=0;d<3;++d)
      afc[d] = __builtin_amdgcn_mfma_f32_16x16x32_bf16(a5, bx[d], afc[d], 0,0,0);
  }
  if (w < 4) {
    f32x4 as2;
    {
      f32x4 bv1 = *(const f32x4*)&vs_b[obA];
      f32x4 bv2 = *(const f32x4*)&ss_b[obA];
      as2 = (f32x4){bv1[0]+bv2[0], bv1[1]+bv2[1], bv1[2]+bv2[2], bv1[3]+bv2[3]};
    }
#pragma unroll
    for (int ks=0;ks<4;++ks) {
      bf16x8 a6 = wv[11264 + (w*4+ks)*64 + l];
      as2 = __builtin_amdgcn_mfma_f32_16x16x32_bf16(a6, vfv_p[ks*64+l], as2, 0,0,0);
    }
#pragma unroll
    for (int ks=0;ks<2;++ks) {
      bf16x8 a7 = wv[12288 + (w*2+ks)*64 + l];
      as2 = __builtin_amdgcn_mfma_f32_16x16x32_bf16(a7, sfv_p[ks*64+l], as2, 0,0,0);
    }
#pragma unroll
    for (int r=0;r<4;++r)
      out_s[sbase + (size_t)(obA+r)*4096 + c15] = as2[r];
  }

  // ---- epilogue: direct global stores (v) ----
#pragma unroll
  for (int d=0;d<3;++d)
#pragma unroll
    for (int r=0;r<4;++r)
      out_v[vbase + (size_t)((obA+r)*3 + d)*4096 + c15] = afc[d][r];
}

extern "C" void kernel_launch(void* const* d_in, const int* in_sizes, int n_in,
                              void* d_out, int out_size, void* d_ws, size_t ws_size,
                              hipStream_t stream) {
  (void)in_sizes; (void)n_in; (void)out_size; (void)ws_size;
  const float* v_in      = (const float*)d_in[0];
  const float* s_in      = (const float*)d_in[1];
  const float* weight    = (const float*)d_in[2];
  const float* sv_w      = (const float*)d_in[3];
  const float* sv_b      = (const float*)d_in[4];
  const float* cross_w   = (const float*)d_in[5];
  const float* cross_b   = (const float*)d_in[6];
  const float* crossfc_w = (const float*)d_in[7];
  const float* crossfc_b = (const float*)d_in[8];
  const float* vsdir_w   = (const float*)d_in[9];
  const float* vsdir_b   = (const float*)d_in[10];
  const float* vs_w      = (const float*)d_in[11];
  const float* vs_b      = (const float*)d_in[12];
  const float* ss_w      = (const float*)d_in[13];
  const float* ss_b      = (const float*)d_in[14];

  unsigned short* wsb = (unsigned short*)d_ws;
  float* wsf = (float*)((char*)d_ws + 204800);

  kprep0<<<16, 256, 0, stream>>>(weight, cross_w, crossfc_w, vsdir_w,
                                 cross_b, crossfc_b, vsdir_b, wsf);
  kprep1<<<64, 256, 0, stream>>>(weight, sv_w, cross_w, crossfc_w, vsdir_w,
                                 vs_w, ss_w, wsb, wsf);
  dim3 grid(4096/16, 8);
  kmain<<<grid, 512, 0, stream>>>(v_in, s_in, sv_b, vs_b, ss_b, wsb, wsf,
                                  (float*)d_out, (float*)d_out + VOUT_ELEMS);
}